// Round 5
// baseline (834.742 us; speedup 1.0000x reference)
//
#include <hip/hip_runtime.h>
#include <math.h>

// AdditiveAttention: B=64, L=1024, Q=K=H=1024, fp32 in/out.
// Round 5: attack k2's three measured sinks: LDS bank conflicts (1.5e8 cyc ~ 50%),
// fp32->bf16 conversion VALU (64 scalar cvt/thread/iter), cross-XCD A-tile refetch
// (FETCH 4x keys). W2 pre-converted to bf16 in d_ws IF ws_size allows (checked!).
//
//   out[0..65536):      k0 zeroes; k1 atomicAdds q = query@W1^T; k3 zeroes; k4 stores context.
//   out[65536..131072): k0 zeroes; k2 atomicAdds scores; k3 overwrites with softmax weights.
//   ws[0..2 MB):        kconv writes W2 as bf16 (only if ws_size >= 2 MB + slack).

typedef __attribute__((ext_vector_type(8))) short short8;     // 8 bf16 = 4 VGPRs (A/B frag)
typedef __attribute__((ext_vector_type(4))) float floatx4;    // 4 fp32 (C/D frag)
typedef __attribute__((ext_vector_type(8))) float float8v;
typedef __attribute__((ext_vector_type(8))) __bf16 bf16x8;

__device__ __forceinline__ short8 cvt8(float4 lo, float4 hi) {  // 8x fp32 -> bf16 RNE, packed
    float8v f = {lo.x, lo.y, lo.z, lo.w, hi.x, hi.y, hi.z, hi.w};
    bf16x8 b = __builtin_convertvector(f, bf16x8);
    union { bf16x8 b; short8 s; } u; u.b = b;
    return u.s;
}

// ---------------- k0: zero the whole output buffer (131072 floats) ----------------
__global__ __launch_bounds__(256) void k0_zero(float* __restrict__ out) {
    const int i = (blockIdx.x * 256 + threadIdx.x) * 4;
    const float4 z = {0.f, 0.f, 0.f, 0.f};
    *(float4*)(out + i) = z;
}

// ---------------- kconv: W2 (1M fp32) -> bf16 in ws ----------------
__global__ __launch_bounds__(256) void kconv_w2(const float* __restrict__ W2,
                                                unsigned short* __restrict__ W2b) {
    const int i = (blockIdx.x * 256 + threadIdx.x) * 8;
    const float4 lo = *(const float4*)(W2 + i);
    const float4 hi = *(const float4*)(W2 + i + 4);
    *(short8*)(W2b + i) = cvt8(lo, hi);
}

// ------- k1: q += query @ W1^T (BM=64 b, BN=64 h, BK=32), K split x4, atomicAdd -------
__global__ __launch_bounds__(256) void k1_qproj(
    const float* __restrict__ query, const float* __restrict__ W1,
    float* __restrict__ out)
{
    __shared__ float As[32][64];   // [k][b]
    __shared__ float Bs[32][64];   // [k][h]
    const int t  = threadIdx.x;
    const int tx = t & 15, ty = t >> 4;
    const int h0 = blockIdx.x * 64;
    const int kbase = blockIdx.y * 256;
    const int sr = t >> 2;          // staging row 0..63
    const int sk = (t & 3) * 8;     // staging k offset {0,8,16,24}
    float c[4][4] = {{0.f}};
    for (int k0 = kbase; k0 < kbase + 256; k0 += 32) {
        const float4 a0 = *(const float4*)(query + sr * 1024 + k0 + sk);
        const float4 a1 = *(const float4*)(query + sr * 1024 + k0 + sk + 4);
        const float4 b0 = *(const float4*)(W1 + (h0 + sr) * 1024 + k0 + sk);
        const float4 b1 = *(const float4*)(W1 + (h0 + sr) * 1024 + k0 + sk + 4);
        __syncthreads();
        As[sk+0][sr]=a0.x; As[sk+1][sr]=a0.y; As[sk+2][sr]=a0.z; As[sk+3][sr]=a0.w;
        As[sk+4][sr]=a1.x; As[sk+5][sr]=a1.y; As[sk+6][sr]=a1.z; As[sk+7][sr]=a1.w;
        Bs[sk+0][sr]=b0.x; Bs[sk+1][sr]=b0.y; Bs[sk+2][sr]=b0.z; Bs[sk+3][sr]=b0.w;
        Bs[sk+4][sr]=b1.x; Bs[sk+5][sr]=b1.y; Bs[sk+6][sr]=b1.z; Bs[sk+7][sr]=b1.w;
        __syncthreads();
        #pragma unroll
        for (int k = 0; k < 32; ++k) {
            const float4 av = *(const float4*)&As[k][ty*4];
            const float4 bv = *(const float4*)&Bs[k][tx*4];
            const float aa[4] = {av.x, av.y, av.z, av.w};
            const float bb[4] = {bv.x, bv.y, bv.z, bv.w};
            #pragma unroll
            for (int i = 0; i < 4; ++i)
                #pragma unroll
                for (int j = 0; j < 4; ++j)
                    c[i][j] = fmaf(aa[i], bb[j], c[i][j]);
        }
    }
    #pragma unroll
    for (int i = 0; i < 4; ++i)
        #pragma unroll
        for (int j = 0; j < 4; ++j)
            atomicAdd(&out[(ty*4 + i) * 1024 + h0 + tx*4 + j], c[i][j]);
}

// --------- k2: bf16-MFMA keys@W2^T (128x128 tile) + fused tanh-dot-v epilogue ---------
// Flat grid 4096, XCD-aware: lt = id&7 (XCD tag under id%8 round-robin), then hb
// fastest so the 8 hb-siblings of one A-tile run back-to-back on one XCD.
// LDS: unpadded 64 B rows + XOR swizzle (phys chunk = logical ^ ((row>>1)&3)):
// both staging writes and frag reads hit all 8 bank-slots uniformly (structural min).
__global__ __launch_bounds__(256) void k2_scores(
    const float* __restrict__ keys, const float* __restrict__ W2,
    const unsigned short* __restrict__ W2b, const float* __restrict__ v,
    float* __restrict__ out, int w2bf)
{
    __shared__ union {
        struct { short A[128][32]; short B[128][32]; } st;  // 16.0 KB staging
        float red[128][33];                                 // 16.5 KB epilogue overlay
    } sm;
    const int t  = threadIdx.x;
    const int id = blockIdx.x;
    const int lt = id & 7;            // XCD tag
    const int n  = id >> 3;
    const int hb = n & 7;             // fastest within an XCD's queue
    const int b  = n >> 3;            // 0..63
    const int l0 = lt * 128;
    const int h0 = hb * 128;
    const float* q = out;             // written by k1
    float* score = out + 65536;       // zeroed by k0

    // staging: thread t owns row r = t>>1, logical chunks {ch, ch+1} (16 floats / 32 B bf16)
    const int r  = t >> 1;
    const int ch = (t & 1) * 2;
    const int xr = (r >> 1) & 3;                    // row swizzle key
    const int p0 = (ch    ) ^ xr;                   // physical chunk slots
    const int p1 = (ch + 1) ^ xr;
    const float*          Arow = keys + ((size_t)(b * 1024 + l0 + r)) * 1024 + ch * 8;
    const float*          Bfrow = W2  + ((size_t)(h0 + r)) * 1024 + ch * 8;
    const unsigned short* Bbrow = W2b + ((size_t)(h0 + r)) * 1024 + ch * 8;

    // MFMA lane mapping (verified m89/m91): A/B frag [lane&15][quad*8+j]; C/D col=lane&15,row=quad*4+reg
    const int lane = t & 63, wid = t >> 6;
    const int quad = lane >> 4, m16 = lane & 15;
    const int wm = (wid >> 1) * 64;     // wave's m (l) origin
    const int wn = (wid & 1) * 64;      // wave's n (h) origin
    const int xf = (m16 >> 1) & 3;      // frag-read swizzle key ((R>>1)&3 reduces to this)
    const int pa = quad ^ xf;           // physical chunk for frag reads

    floatx4 acc[4][4] = {};

    for (int kk = 0; kk < 1024; kk += 32) {
        const float4 a0 = *(const float4*)(Arow + kk);
        const float4 a1 = *(const float4*)(Arow + kk + 4);
        const float4 a2 = *(const float4*)(Arow + kk + 8);
        const float4 a3 = *(const float4*)(Arow + kk + 12);
        short8 bs0, bs1;
        if (w2bf) {
            bs0 = *(const short8*)(Bbrow + kk);
            bs1 = *(const short8*)(Bbrow + kk + 8);
        } else {
            const float4 w0 = *(const float4*)(Bfrow + kk);
            const float4 w1 = *(const float4*)(Bfrow + kk + 4);
            const float4 w2_ = *(const float4*)(Bfrow + kk + 8);
            const float4 w3 = *(const float4*)(Bfrow + kk + 12);
            bs0 = cvt8(w0, w1);
            bs1 = cvt8(w2_, w3);
        }
        __syncthreads();   // prior iteration's frag reads complete before overwrite
        *(short8*)&sm.st.A[r][p0 * 8] = cvt8(a0, a1);
        *(short8*)&sm.st.A[r][p1 * 8] = cvt8(a2, a3);
        *(short8*)&sm.st.B[r][p0 * 8] = bs0;
        *(short8*)&sm.st.B[r][p1 * 8] = bs1;
        __syncthreads();
        short8 af[4], bf[4];
        #pragma unroll
        for (int i = 0; i < 4; ++i)
            af[i] = *(const short8*)&sm.st.A[wm + i*16 + m16][pa * 8];
        #pragma unroll
        for (int j = 0; j < 4; ++j)
            bf[j] = *(const short8*)&sm.st.B[wn + j*16 + m16][pa * 8];
        #pragma unroll
        for (int i = 0; i < 4; ++i)
            #pragma unroll
            for (int j = 0; j < 4; ++j)
                acc[i][j] = __builtin_amdgcn_mfma_f32_16x16x32_bf16(af[i], bf[j], acc[i][j], 0, 0, 0);
    }

    // epilogue: s[l] = sum_h tanh(q[b,h] + D[l,h]) * v[h] over this block's 128 h
    float qv[4], vv[4];
    #pragma unroll
    for (int j = 0; j < 4; ++j) {
        const int h = h0 + wn + j * 16 + m16;   // C/D col for n-tile j
        qv[j] = q[b * 1024 + h];
        vv[j] = v[h];
    }
    __syncthreads();   // staging reads done before red overlay
    #pragma unroll
    for (int i = 0; i < 4; ++i) {
        #pragma unroll
        for (int rr = 0; rr < 4; ++rr) {
            float s = 0.f;
            #pragma unroll
            for (int j = 0; j < 4; ++j)
                s += tanhf(qv[j] + acc[i][j][rr]) * vv[j];
            // C/D row for m-tile i, reg rr: wm + i*16 + quad*4 + rr
            sm.red[wm + i * 16 + quad * 4 + rr][(wid & 1) * 16 + m16] = s;
        }
    }
    __syncthreads();
    if (t < 128) {
        const float* rw = sm.red[t];
        float s = 0.f;
        #pragma unroll
        for (int c = 0; c < 32; ++c) s += rw[c];
        atomicAdd(&score[b * 1024 + l0 + t], s);   // accumulate over 8 hb blocks
    }
}

// --------- k3: mask, softmax in-place over score region; zero context row ---------
__global__ __launch_bounds__(256) void k3_softmax(
    const unsigned char* __restrict__ mask_u8, float* __restrict__ out)
{
    __shared__ float sc[1024];
    __shared__ float red[256];
    __shared__ int nz_sh;
    const int b = blockIdx.x;
    const int t = threadIdx.x;

    // inline mask-dtype sniff over the first 1024 bytes (safe for u8 or i32):
    // int32 0/1 data has zero bytes at positions i%4 != 0.
    if (t == 0) nz_sh = 0;
    __syncthreads();
    {
        int nz = 0;
        #pragma unroll
        for (int j = 1; j < 4; ++j)
            if (mask_u8[t * 4 + j] != 0) nz = 1;
        if (nz) atomicAdd(&nz_sh, 1);
    }
    __syncthreads();
    const int use_i32 = (nz_sh == 0);
    const int* mask_i32 = (const int*)mask_u8;

    float* score = out + 65536;
    float lmax = -INFINITY;
    #pragma unroll
    for (int i = 0; i < 4; ++i) {
        const int l = t + i * 256;
        float s = score[b * 1024 + l];
        const int ml = b * 1024 + l;
        const bool masked = use_i32 ? (mask_i32[ml] != 0) : (mask_u8[ml] != 0);
        if (masked) s = -INFINITY;   // where(mask, -inf, s)
        sc[l] = s;
        lmax = fmaxf(lmax, s);
    }
    red[t] = lmax;
    __syncthreads();
    for (int off = 128; off > 0; off >>= 1) {
        if (t < off) red[t] = fmaxf(red[t], red[t + off]);
        __syncthreads();
    }
    const float m = red[0];
    __syncthreads();
    float e[4];
    float lsum = 0.f;
    #pragma unroll
    for (int i = 0; i < 4; ++i) {
        const float s = sc[t + i * 256];
        const float ev = (s > -INFINITY && m > -INFINITY) ? expf(s - m) : 0.f;
        e[i] = ev;
        lsum += ev;
    }
    red[t] = lsum;
    __syncthreads();
    for (int off = 128; off > 0; off >>= 1) {
        if (t < off) red[t] += red[t + off];
        __syncthreads();
    }
    const float S = red[0];
    const float inv = (S > 0.f) ? (1.f / S) : 0.f;   // all-masked row -> weights 0 (nan_to_num)
    #pragma unroll
    for (int i = 0; i < 4; ++i)
        score[b * 1024 + t + i * 256] = e[i] * inv;  // weights, in place
    // zero context row for k4 (k4 overwrites anyway; cheap safety)
    const float4 z = {0.f, 0.f, 0.f, 0.f};
    ((float4*)(out + b * 1024))[t] = z;
}

// --------- k4: context[b, kc*128 .. +128) = sum_l w[b,l]*keys[b,l,k] — atomic-free ---------
// grid (8 k-chunks, 64 b): each block owns a unique (b, k-range): direct store.
__global__ __launch_bounds__(256) void k4_context(
    const float* __restrict__ keys, float* __restrict__ out)
{
    __shared__ float w[1024];
    __shared__ float4 part[8][32];
    const int t  = threadIdx.x;
    const int kc = blockIdx.x;      // 0..7 (128 floats = 32 float4 each)
    const int b  = blockIdx.y;
    #pragma unroll
    for (int i = 0; i < 4; ++i)
        w[t + i * 256] = out[65536 + b * 1024 + t + i * 256];
    __syncthreads();
    const int r8 = t >> 5;          // 0..7 l-phase
    const int c4 = t & 31;          // float4 column within chunk
    const float4* kp = (const float4*)(keys + (size_t)b * 1048576) + kc * 32 + c4;
    float4 acc = {0.f, 0.f, 0.f, 0.f};
    #pragma unroll 8
    for (int l = r8; l < 1024; l += 8) {
        const float4 kv = kp[(size_t)l * 256];
        const float wv = w[l];
        acc.x = fmaf(wv, kv.x, acc.x);
        acc.y = fmaf(wv, kv.y, acc.y);
        acc.z = fmaf(wv, kv.z, acc.z);
        acc.w = fmaf(wv, kv.w, acc.w);
    }
    part[r8][c4] = acc;
    __syncthreads();
    if (t < 32) {
        float4 s = part[0][t];
        #pragma unroll
        for (int rr = 1; rr < 8; ++rr) {
            const float4 pv = part[rr][t];
            s.x += pv.x; s.y += pv.y; s.z += pv.z; s.w += pv.w;
        }
        *(float4*)(out + b * 1024 + kc * 128 + t * 4) = s;
    }
}

extern "C" void kernel_launch(void* const* d_in, const int* in_sizes, int n_in,
                              void* d_out, int out_size, void* d_ws, size_t ws_size,
                              hipStream_t stream) {
    const float*         query = (const float*)d_in[0];
    const float*         keys  = (const float*)d_in[1];
    const unsigned char* mask  = (const unsigned char*)d_in[2];  // bool: u8 or i32, sniffed in k3
    const float*         W1    = (const float*)d_in[3];
    const float*         W2    = (const float*)d_in[4];
    const float*         v     = (const float*)d_in[5];
    float* out = (float*)d_out;   // [0..65536) context, [65536..131072) weights

    // W2-bf16 cache in ws ONLY if the workspace is provably large enough.
    const bool  w2ws = (ws_size >= (size_t)(2 * 1024 * 1024 + 64));
    unsigned short* W2b = (unsigned short*)d_ws;

    k0_zero   <<<dim3(128),     256, 0, stream>>>(out);
    if (w2ws)
        kconv_w2<<<dim3(512),   256, 0, stream>>>(W2, W2b);
    k1_qproj  <<<dim3(16, 4),   256, 0, stream>>>(query, W1, out);
    k2_scores <<<dim3(4096),    256, 0, stream>>>(keys, W2, w2ws ? W2b : (unsigned short*)nullptr,
                                                  v, out, w2ws ? 1 : 0);
    k3_softmax<<<dim3(64),      256, 0, stream>>>(mask, out);
    k4_context<<<dim3(8, 64),   256, 0, stream>>>(keys, out);
}